// Round 1
// baseline (1587.016 us; speedup 1.0000x reference)
//
#include <hip/hip_runtime.h>

#define D 512
#define TPB 256

// ---------------- GEMM: C[M,N] = A[M,K] @ W[K,N] + bias[N] ----------------
// BM=64, BN=64, BK=16, 256 threads, 4x4 per thread. Requires N%64==0, K%16==0.
#define BM 64
#define BN 64
#define BK 16

__global__ __launch_bounds__(256) void gemm_bias(
    const float* __restrict__ A, const float* __restrict__ W,
    const float* __restrict__ bias, float* __restrict__ C,
    int M, int N, int K) {
  __shared__ float As[BK][BM];  // transposed A tile
  __shared__ float Bs[BK][BN];
  const int tid = threadIdx.x;
  const int m0 = blockIdx.y * BM;
  const int n0 = blockIdx.x * BN;
  const int tx = tid & 15;
  const int ty = tid >> 4;
  const int arow = tid >> 2;          // 0..63
  const int akq = (tid & 3) * 4;      // 0,4,8,12
  const int brow = tid >> 4;          // 0..15
  const int bnq = (tid & 15) * 4;     // 0..60
  float acc[4][4] = {};
  for (int k0 = 0; k0 < K; k0 += BK) {
    float4 av;
    const int gm = m0 + arow;
    if (gm < M)
      av = *reinterpret_cast<const float4*>(&A[(size_t)gm * K + k0 + akq]);
    else
      av = make_float4(0.f, 0.f, 0.f, 0.f);
    As[akq + 0][arow] = av.x;
    As[akq + 1][arow] = av.y;
    As[akq + 2][arow] = av.z;
    As[akq + 3][arow] = av.w;
    *reinterpret_cast<float4*>(&Bs[brow][bnq]) =
        *reinterpret_cast<const float4*>(&W[(size_t)(k0 + brow) * N + n0 + bnq]);
    __syncthreads();
#pragma unroll
    for (int k = 0; k < BK; ++k) {
      const float4 a4 = *reinterpret_cast<const float4*>(&As[k][ty * 4]);
      const float4 b4 = *reinterpret_cast<const float4*>(&Bs[k][tx * 4]);
      const float a[4] = {a4.x, a4.y, a4.z, a4.w};
      const float b[4] = {b4.x, b4.y, b4.z, b4.w};
#pragma unroll
      for (int i = 0; i < 4; ++i)
#pragma unroll
        for (int j = 0; j < 4; ++j) acc[i][j] += a[i] * b[j];
    }
    __syncthreads();
  }
#pragma unroll
  for (int i = 0; i < 4; ++i) {
    const int gm = m0 + ty * 4 + i;
    if (gm >= M) continue;
#pragma unroll
    for (int j = 0; j < 4; ++j) {
      const int gn = n0 + tx * 4 + j;
      C[(size_t)gm * N + gn] = acc[i][j] + bias[gn];
    }
  }
}

// ---------------- per-row double dot: sd[r]=h[r]@w[:D], ss[r]=h[r]@w[D:] ----
__global__ __launch_bounds__(256) void rowdot2(
    const float* __restrict__ h, const float* __restrict__ w_att,
    float* __restrict__ sd, float* __restrict__ ss) {
  const int r = blockIdx.x;
  const int t = threadIdx.x;
  const float v0 = h[(size_t)r * D + t];
  const float v1 = h[(size_t)r * D + t + 256];
  float psd = v0 * w_att[t] + v1 * w_att[t + 256];
  float pss = v0 * w_att[D + t] + v1 * w_att[D + t + 256];
  __shared__ float s1[256], s2[256];
  s1[t] = psd;
  s2[t] = pss;
  __syncthreads();
  for (int off = 128; off > 0; off >>= 1) {
    if (t < off) {
      s1[t] += s1[t + off];
      s2[t] += s2[t + off];
    }
    __syncthreads();
  }
  if (t == 0) {
    sd[r] = s1[0];
    ss[r] = s2[0];
  }
}

// ---------------- CSR build ----------------
__global__ void count_deg(const int* __restrict__ di, int* __restrict__ deg, int E) {
  const int e = blockIdx.x * blockDim.x + threadIdx.x;
  if (e < E) atomicAdd(&deg[di[e]], 1);
}

__global__ __launch_bounds__(256) void exscan_kernel(
    const int* __restrict__ deg, int* __restrict__ row_start,
    int* __restrict__ cursor, int n) {
  __shared__ int buf[256];
  const int t = threadIdx.x;
  int carry = 0;
  for (int base = 0; base < n; base += 256) {
    const int i = base + t;
    const int v = (i < n) ? deg[i] : 0;
    buf[t] = v;
    __syncthreads();
    for (int off = 1; off < 256; off <<= 1) {
      const int y = (t >= off) ? buf[t - off] : 0;
      __syncthreads();
      buf[t] += y;
      __syncthreads();
    }
    const int excl = carry + buf[t] - v;
    if (i < n) {
      row_start[i] = excl;
      cursor[i] = excl;
    }
    carry += buf[255];
    __syncthreads();
  }
  if (t == 0) row_start[n] = carry;
}

__global__ void fill_csr(const int* __restrict__ di, const int* __restrict__ si,
                         int* __restrict__ cursor, int* __restrict__ csr_src, int E) {
  const int e = blockIdx.x * blockDim.x + threadIdx.x;
  if (e < E) {
    const int p = atomicAdd(&cursor[di[e]], 1);
    csr_src[p] = si[e];
  }
}

// ---------------- GAT softmax + aggregate, fused feat update ----------------
// one block (256 threads) per destination node
__global__ __launch_bounds__(256) void gat_aggregate(
    float* __restrict__ feat, const float* __restrict__ h,
    const float* __restrict__ sd, const float* __restrict__ ss,
    const float* __restrict__ b_att_p, const float* __restrict__ gat_bias,
    const int* __restrict__ row_start, const int* __restrict__ csr_src) {
  const int dst = blockIdx.x;
  const int t = threadIdx.x;
  const int beg = row_start[dst];
  const int end = row_start[dst + 1];
  const float sdd = sd[dst];
  const float ba = b_att_p[0];
  __shared__ float red[256];
  // phase 1: max
  float m = -1e30f;
  for (int j = beg + t; j < end; j += 256) {
    const float e = tanhf(sdd + ss[csr_src[j]] + ba);
    m = fmaxf(m, e);
  }
  red[t] = m;
  __syncthreads();
  for (int off = 128; off > 0; off >>= 1) {
    if (t < off) red[t] = fmaxf(red[t], red[t + off]);
    __syncthreads();
  }
  m = red[0];
  __syncthreads();
  // phase 2: sum of exp
  float s = 0.f;
  for (int j = beg + t; j < end; j += 256) {
    const float e = tanhf(sdd + ss[csr_src[j]] + ba);
    s += expf(e - m);
  }
  red[t] = s;
  __syncthreads();
  for (int off = 128; off > 0; off >>= 1) {
    if (t < off) red[t] += red[t + off];
    __syncthreads();
  }
  const float denom = red[0];
  const float inv = (denom > 0.f) ? 1.f / denom : 0.f;
  // phase 3: weighted aggregation (serial over edges, all threads on columns)
  float acc0 = 0.f, acc1 = 0.f;
  for (int j = beg; j < end; ++j) {
    const int sidx = csr_src[j];
    const float e = tanhf(sdd + ss[sidx] + ba);
    const float w = expf(e - m) * inv;
    acc0 += w * h[(size_t)sidx * D + t];
    acc1 += w * h[(size_t)sidx * D + t + 256];
  }
  const size_t o = (size_t)dst * D + t;
  feat[o] = (feat[o] + acc0 + gat_bias[t]) * 0.5f;
  feat[o + 256] = (feat[o + 256] + acc1 + gat_bias[t + 256]) * 0.5f;
}

// ---------------- gather rows ----------------
__global__ __launch_bounds__(256) void gather_rows(
    const float* __restrict__ feat, const int* __restrict__ idx,
    float* __restrict__ out) {
  const int b = blockIdx.x;
  const int t = threadIdx.x;
  const int r = idx[b];
  out[(size_t)b * D + t] = feat[(size_t)r * D + t];
  out[(size_t)b * D + t + 256] = feat[(size_t)r * D + t + 256];
}

// ---------------- fused tanh + LayerNorm: out = LN(tanh(xa (+ xb)))*g+beta ---
__global__ __launch_bounds__(256) void tanh_ln(
    const float* __restrict__ xa, const float* __restrict__ xb,
    const float* __restrict__ g, const float* __restrict__ beta,
    float* __restrict__ out) {
  const int r = blockIdx.x;
  const int t = threadIdx.x;
  float v0 = xa[(size_t)r * D + t];
  float v1 = xa[(size_t)r * D + t + 256];
  if (xb) {
    v0 += xb[(size_t)r * D + t];
    v1 += xb[(size_t)r * D + t + 256];
  }
  v0 = tanhf(v0);
  v1 = tanhf(v1);
  __shared__ float s1[256], s2[256];
  s1[t] = v0 + v1;
  s2[t] = v0 * v0 + v1 * v1;
  __syncthreads();
  for (int off = 128; off > 0; off >>= 1) {
    if (t < off) {
      s1[t] += s1[t + off];
      s2[t] += s2[t + off];
    }
    __syncthreads();
  }
  const float mean = s1[0] * (1.f / (float)D);
  const float var = s2[0] * (1.f / (float)D) - mean * mean;
  const float rs = rsqrtf(var + 1e-5f);
  out[(size_t)r * D + t] = (v0 - mean) * rs * g[t] + beta[t];
  out[(size_t)r * D + t + 256] = (v1 - mean) * rs * g[t + 256] + beta[t + 256];
}

// ---------------- final logits + sigmoid ----------------
__global__ __launch_bounds__(256) void final_logit(
    const float* __restrict__ h, const float* __restrict__ Wc,
    const float* __restrict__ bc, float* __restrict__ out) {
  const int r = blockIdx.x;
  const int t = threadIdx.x;
  float p = h[(size_t)r * D + t] * Wc[t] + h[(size_t)r * D + t + 256] * Wc[t + 256];
  __shared__ float red[256];
  red[t] = p;
  __syncthreads();
  for (int off = 128; off > 0; off >>= 1) {
    if (t < off) red[t] += red[t + off];
    __syncthreads();
  }
  if (t == 0) out[r] = 1.f / (1.f + expf(-(red[0] + bc[0])));
}

extern "C" void kernel_launch(void* const* d_in, const int* in_sizes, int n_in,
                              void* d_out, int out_size, void* d_ws, size_t ws_size,
                              hipStream_t stream) {
  (void)n_in; (void)out_size; (void)ws_size;
  const float* node_feat = (const float*)d_in[0];
  const int* edge0 = (const int*)d_in[1];
  const int* edge1 = (const int*)d_in[2];
  const int* tidx = (const int*)d_in[3];
  const float* Wt = (const float*)d_in[4];
  const float* bt = (const float*)d_in[5];
  const float* Wf = (const float*)d_in[6];
  const float* bfp = (const float*)d_in[7];
  const float* w_att = (const float*)d_in[8];
  const float* b_att = (const float*)d_in[9];
  const float* gat_bias = (const float*)d_in[10];
  const float* Wp = (const float*)d_in[11];
  const float* bp = (const float*)d_in[12];
  const float* dnn_W = (const float*)d_in[13];
  const float* dnn_b = (const float*)d_in[14];
  const float* dnn_g = (const float*)d_in[15];
  const float* dnn_be = (const float*)d_in[16];
  const float* res_g = (const float*)d_in[17];
  const float* res_be = (const float*)d_in[18];
  const float* Wc = (const float*)d_in[19];
  const float* bc = (const float*)d_in[20];
  float* out = (float*)d_out;

  const int Nn = in_sizes[0] / D;        // 30000
  const int E = in_sizes[1] / 2;         // 300000
  const int B = in_sizes[3];             // 4096
  const int K_IN = in_sizes[4] / D;      // 512

  char* p = (char*)d_ws;
  auto alloc = [&](size_t bytes) -> char* {
    char* r = p;
    p += (bytes + 255) & ~(size_t)255;
    return r;
  };
  float* feat = (float*)alloc((size_t)Nn * D * 4);
  float* h = (float*)alloc((size_t)Nn * D * 4);
  float* sd = (float*)alloc((size_t)Nn * 4);
  float* ss = (float*)alloc((size_t)Nn * 4);
  int* deg = (int*)alloc((size_t)Nn * 4);
  int* row_start = (int*)alloc((size_t)(Nn + 1) * 4);
  int* cursor = (int*)alloc((size_t)Nn * 4);
  int* csr_src = (int*)alloc((size_t)E * 4);
  float* hb0 = (float*)alloc((size_t)B * D * 4);
  float* hb1 = (float*)alloc((size_t)B * D * 4);
  float* hb2 = (float*)alloc((size_t)B * D * 4);

  dim3 blk(256);

  // 1. feat = node_feat @ Wt + bt
  {
    dim3 grid(D / BN, (Nn + BM - 1) / BM);
    gemm_bias<<<grid, blk, 0, stream>>>(node_feat, Wt, bt, feat, Nn, D, K_IN);
  }

  // 2. two GAT hops: hop1 then hop0
  const int* hops[2] = {edge1, edge0};
  for (int hp = 0; hp < 2; ++hp) {
    const int* di = hops[hp];
    const int* si = hops[hp] + E;
    dim3 gridg(D / BN, (Nn + BM - 1) / BM);
    gemm_bias<<<gridg, blk, 0, stream>>>(feat, Wf, bfp, h, Nn, D, D);
    rowdot2<<<Nn, blk, 0, stream>>>(h, w_att, sd, ss);
    hipMemsetAsync(deg, 0, (size_t)Nn * 4, stream);
    count_deg<<<(E + 255) / 256, blk, 0, stream>>>(di, deg, E);
    exscan_kernel<<<1, blk, 0, stream>>>(deg, row_start, cursor, Nn);
    fill_csr<<<(E + 255) / 256, blk, 0, stream>>>(di, si, cursor, csr_src, E);
    gat_aggregate<<<Nn, blk, 0, stream>>>(feat, h, sd, ss, b_att, gat_bias,
                                          row_start, csr_src);
  }

  // 3. head
  gather_rows<<<B, blk, 0, stream>>>(feat, tidx, hb0);
  dim3 gridh(D / BN, (B + BM - 1) / BM);
  gemm_bias<<<gridh, blk, 0, stream>>>(hb0, Wp, bp, hb1, B, D, D);

  float* cur = hb1;
  float* fa = hb0;
  float* fb = hb2;
  for (int r = 0; r < 2; ++r) {
    for (int i = 0; i < 2; ++i) {
      const int idx = r * 2 + i;
      const float* src = (i == 0) ? cur : fb;
      gemm_bias<<<gridh, blk, 0, stream>>>(src, dnn_W + (size_t)idx * D * D,
                                           dnn_b + (size_t)idx * D, fa, B, D, D);
      tanh_ln<<<B, blk, 0, stream>>>(fa, nullptr, dnn_g + (size_t)idx * D,
                                     dnn_be + (size_t)idx * D, fb);
    }
    tanh_ln<<<B, blk, 0, stream>>>(cur, fb, res_g + (size_t)r * D,
                                   res_be + (size_t)r * D, fa);
    float* t = cur;
    cur = fa;
    fa = t;
  }
  final_logit<<<B, blk, 0, stream>>>(cur, Wc, bc, out);
}

// Round 2
// 677.017 us; speedup vs baseline: 2.3441x; 2.3441x over previous
//
#include <hip/hip_runtime.h>

#define D 512
typedef unsigned short ushort_t;
typedef __attribute__((ext_vector_type(8))) short bf16x8;
typedef __attribute__((ext_vector_type(4))) float f32x4;

static __device__ __forceinline__ ushort_t f2bf(float f) {
  unsigned u = __float_as_uint(f);
  u += 0x7fffu + ((u >> 16) & 1u);  // RNE
  return (ushort_t)(u >> 16);
}
static __device__ __forceinline__ float bf2f(ushort_t h) {
  return __uint_as_float(((unsigned)h) << 16);
}

static __device__ __forceinline__ void gld_lds16(const void* g, void* lds) {
  __builtin_amdgcn_global_load_lds(
      (const __attribute__((address_space(1))) unsigned int*)g,
      (__attribute__((address_space(3))) unsigned int*)lds, 16, 0, 0);
}

// ---------- weight pack: W[K][N] fp32 -> fragment-ready bf16 ----------
// dst[((nt*(K/32)+kt)*512) + (kg*16+col)*8 + j] = W[kt*32+kg*8+j][nt*16+col]
__global__ __launch_bounds__(256) void pack_weight(
    const float* __restrict__ W, ushort_t* __restrict__ out, int K, int N) {
  int i = blockIdx.x * 256 + threadIdx.x;
  if (i >= K * N) return;
  const int k = i / N, n = i - k * N;
  const int nt = n >> 4, col = n & 15, kt = k >> 5, kg = (k >> 3) & 3, j = k & 7;
  out[(((size_t)nt * (K >> 5) + kt) << 9) + ((kg << 4) + col) * 8 + j] = f2bf(W[i]);
}

// ---------- fp32 -> bf16 row-major with row padding ----------
__global__ __launch_bounds__(256) void conv_bf16_pad(
    const float* __restrict__ in, ushort_t* __restrict__ out, int M, int Mp, int K) {
  const size_t i4 = ((size_t)blockIdx.x * 256 + threadIdx.x) * 4;
  if (i4 >= (size_t)Mp * K) return;
  const int row = (int)(i4 / K);
  ushort4 o;
  if (row < M) {
    const float4 v = *reinterpret_cast<const float4*>(&in[i4]);
    o.x = f2bf(v.x); o.y = f2bf(v.y); o.z = f2bf(v.z); o.w = f2bf(v.w);
  } else {
    o.x = o.y = o.z = o.w = 0;
  }
  *reinterpret_cast<ushort4*>(&out[i4]) = o;
}

// ---------- MFMA GEMM: C[Mp,N] = A[Mp,K](bf16) @ Wpack + bias ----------
// 128x128 tile, 4 waves (2x2), BK=32, fragment-ready LDS staging.
__global__ __launch_bounds__(256) void gemm_mfma(
    const ushort_t* __restrict__ A, const ushort_t* __restrict__ Bp,
    const float* __restrict__ bias, float* __restrict__ C32,
    ushort_t* __restrict__ C16, int N, int K) {
  __shared__ __align__(16) ushort_t As[8 * 512];
  __shared__ __align__(16) ushort_t Bs[8 * 512];
  const int tid = threadIdx.x;
  const int lane = tid & 63;
  const int wid = tid >> 6;
  const int m0 = blockIdx.y * 128;
  const int n0 = blockIdx.x * 128;
  const int wm = wid >> 1, wn = wid & 1;
  const int arow = lane & 15;
  const int akoff = (lane >> 4) * 8;
  const int kt32 = K >> 5;
  f32x4 acc[4][4] = {};
  ushort_t* as0 = &As[(wid * 2 + 0) * 512];
  ushort_t* as1 = &As[(wid * 2 + 1) * 512];
  ushort_t* bs0 = &Bs[(wid * 2 + 0) * 512];
  ushort_t* bs1 = &Bs[(wid * 2 + 1) * 512];
  for (int k0 = 0; k0 < K; k0 += 32) {
    // A subtiles: rows m0 + sub*16 + (lane&15), k in [k0+akoff, +8)
    const ushort_t* ga0 = &A[(size_t)(m0 + (wid * 2 + 0) * 16 + arow) * K + k0 + akoff];
    const ushort_t* ga1 = &A[(size_t)(m0 + (wid * 2 + 1) * 16 + arow) * K + k0 + akoff];
    gld_lds16(ga0, as0);
    gld_lds16(ga1, as1);
    // B subtiles: packed, lane reads its own 16B
    const ushort_t* gb0 = &Bp[(((size_t)(n0 / 16 + wid * 2 + 0) * kt32 + (k0 >> 5)) << 9) + lane * 8];
    const ushort_t* gb1 = &Bp[(((size_t)(n0 / 16 + wid * 2 + 1) * kt32 + (k0 >> 5)) << 9) + lane * 8];
    gld_lds16(gb0, bs0);
    gld_lds16(gb1, bs1);
    __syncthreads();
    bf16x8 af[4], bf[4];
#pragma unroll
    for (int mi = 0; mi < 4; ++mi)
      af[mi] = *reinterpret_cast<const bf16x8*>(&As[(wm * 4 + mi) * 512 + lane * 8]);
#pragma unroll
    for (int ni = 0; ni < 4; ++ni)
      bf[ni] = *reinterpret_cast<const bf16x8*>(&Bs[(wn * 4 + ni) * 512 + lane * 8]);
#pragma unroll
    for (int mi = 0; mi < 4; ++mi)
#pragma unroll
      for (int ni = 0; ni < 4; ++ni)
        acc[mi][ni] = __builtin_amdgcn_mfma_f32_16x16x32_bf16(af[mi], bf[ni], acc[mi][ni], 0, 0, 0);
    __syncthreads();
  }
  // epilogue: C/D layout col=lane&15, row=(lane>>4)*4+r
#pragma unroll
  for (int mi = 0; mi < 4; ++mi) {
    const int row = m0 + wm * 64 + mi * 16 + ((lane >> 4) << 2);
#pragma unroll
    for (int ni = 0; ni < 4; ++ni) {
      const int col = n0 + wn * 64 + ni * 16 + (lane & 15);
      const float bv = bias[col];
#pragma unroll
      for (int r = 0; r < 4; ++r) {
        const float v = acc[mi][ni][r] + bv;
        const size_t o = (size_t)(row + r) * N + col;
        if (C32) C32[o] = v;
        if (C16) C16[o] = f2bf(v);
      }
    }
  }
}

// ---------- per-row double dot on bf16 h ----------
__global__ __launch_bounds__(256) void rowdot2(
    const ushort_t* __restrict__ hb, const float* __restrict__ w_att,
    float* __restrict__ sd, float* __restrict__ ss) {
  const int r = blockIdx.x;
  const int t = threadIdx.x;
  const ushort2 v = *reinterpret_cast<const ushort2*>(&hb[(size_t)r * D + t * 2]);
  const float v0 = bf2f(v.x), v1 = bf2f(v.y);
  __shared__ float s1[256], s2[256];
  s1[t] = v0 * w_att[t * 2] + v1 * w_att[t * 2 + 1];
  s2[t] = v0 * w_att[D + t * 2] + v1 * w_att[D + t * 2 + 1];
  __syncthreads();
  for (int off = 128; off > 0; off >>= 1) {
    if (t < off) { s1[t] += s1[t + off]; s2[t] += s2[t + off]; }
    __syncthreads();
  }
  if (t == 0) { sd[r] = s1[0]; ss[r] = s2[0]; }
}

// ---------- CSR build ----------
__global__ void count_deg(const int* __restrict__ di, int* __restrict__ deg, int E) {
  const int e = blockIdx.x * blockDim.x + threadIdx.x;
  if (e < E) atomicAdd(&deg[di[e]], 1);
}

__global__ __launch_bounds__(256) void scan_block(
    const int* __restrict__ deg, int* __restrict__ incl, int* __restrict__ bsum, int n) {
  __shared__ int buf[256];
  const int t = threadIdx.x;
  const int i = blockIdx.x * 256 + t;
  const int v = (i < n) ? deg[i] : 0;
  buf[t] = v;
  __syncthreads();
  for (int off = 1; off < 256; off <<= 1) {
    const int y = (t >= off) ? buf[t - off] : 0;
    __syncthreads();
    buf[t] += y;
    __syncthreads();
  }
  if (i < n) incl[i] = buf[t];
  if (t == 255) bsum[blockIdx.x] = buf[255];
}

__global__ __launch_bounds__(256) void scan_sums(
    int* __restrict__ bsum, int nb, int* __restrict__ row_total) {
  __shared__ int buf[256];
  const int t = threadIdx.x;
  const int v = (t < nb) ? bsum[t] : 0;
  buf[t] = v;
  __syncthreads();
  for (int off = 1; off < 256; off <<= 1) {
    const int y = (t >= off) ? buf[t - off] : 0;
    __syncthreads();
    buf[t] += y;
    __syncthreads();
  }
  if (t < nb) bsum[t] = buf[t] - v;  // exclusive
  if (t == 0) *row_total = buf[255];
}

__global__ __launch_bounds__(256) void scan_finalize(
    const int* __restrict__ incl, const int* __restrict__ deg,
    const int* __restrict__ bsum, int* __restrict__ row_start,
    int* __restrict__ cursor, int n) {
  const int i = blockIdx.x * 256 + threadIdx.x;
  if (i >= n) return;
  const int v = incl[i] - deg[i] + bsum[i >> 8];
  row_start[i] = v;
  cursor[i] = v;
}

__global__ void fill_csr(const int* __restrict__ di, const int* __restrict__ si,
                         int* __restrict__ cursor, int* __restrict__ csr_src, int E) {
  const int e = blockIdx.x * blockDim.x + threadIdx.x;
  if (e < E) {
    const int p = atomicAdd(&cursor[di[e]], 1);
    csr_src[p] = si[e];
  }
}

// ---------- GAT softmax + aggregate, bf16 h / bf16 feat ----------
__global__ __launch_bounds__(256) void gat_aggregate(
    ushort_t* __restrict__ featb, const ushort_t* __restrict__ hb,
    const float* __restrict__ sd, const float* __restrict__ ss,
    const float* __restrict__ b_att_p, const float* __restrict__ gat_bias,
    const int* __restrict__ row_start, const int* __restrict__ csr_src) {
  const int dst = blockIdx.x;
  const int t = threadIdx.x;
  const int beg = row_start[dst];
  const int end = row_start[dst + 1];
  const float sdd = sd[dst];
  const float ba = b_att_p[0];
  __shared__ float red[256];
  float m = -1e30f;
  for (int j = beg + t; j < end; j += 256)
    m = fmaxf(m, tanhf(sdd + ss[csr_src[j]] + ba));
  red[t] = m;
  __syncthreads();
  for (int off = 128; off > 0; off >>= 1) {
    if (t < off) red[t] = fmaxf(red[t], red[t + off]);
    __syncthreads();
  }
  m = red[0];
  __syncthreads();
  float s = 0.f;
  for (int j = beg + t; j < end; j += 256)
    s += expf(tanhf(sdd + ss[csr_src[j]] + ba) - m);
  red[t] = s;
  __syncthreads();
  for (int off = 128; off > 0; off >>= 1) {
    if (t < off) red[t] += red[t + off];
    __syncthreads();
  }
  const float denom = red[0];
  const float inv = (denom > 0.f) ? 1.f / denom : 0.f;
  float acc0 = 0.f, acc1 = 0.f;
  for (int j = beg; j < end; ++j) {
    const int sidx = csr_src[j];
    const float w = expf(tanhf(sdd + ss[sidx] + ba) - m) * inv;
    const ushort2 hv = *reinterpret_cast<const ushort2*>(&hb[(size_t)sidx * D + t * 2]);
    acc0 += w * bf2f(hv.x);
    acc1 += w * bf2f(hv.y);
  }
  const size_t o = (size_t)dst * D + t * 2;
  ushort2 fv = *reinterpret_cast<const ushort2*>(&featb[o]);
  const float f0 = (bf2f(fv.x) + acc0 + gat_bias[t * 2]) * 0.5f;
  const float f1 = (bf2f(fv.y) + acc1 + gat_bias[t * 2 + 1]) * 0.5f;
  fv.x = f2bf(f0);
  fv.y = f2bf(f1);
  *reinterpret_cast<ushort2*>(&featb[o]) = fv;
}

// ---------- gather bf16 rows ----------
__global__ __launch_bounds__(256) void gather_rows_b(
    const ushort_t* __restrict__ featb, const int* __restrict__ idx,
    ushort_t* __restrict__ out) {
  const int b = blockIdx.x;
  const int t = threadIdx.x;
  const int r = idx[b];
  *reinterpret_cast<ushort2*>(&out[(size_t)b * D + t * 2]) =
      *reinterpret_cast<const ushort2*>(&featb[(size_t)r * D + t * 2]);
}

// ---------- fused tanh + LayerNorm, fp32 + bf16 outputs ----------
__global__ __launch_bounds__(256) void tanh_ln(
    const float* __restrict__ xa, const float* __restrict__ xb,
    const float* __restrict__ g, const float* __restrict__ beta,
    float* __restrict__ out32, ushort_t* __restrict__ out16) {
  const int r = blockIdx.x;
  const int t = threadIdx.x;
  float v0 = xa[(size_t)r * D + t];
  float v1 = xa[(size_t)r * D + t + 256];
  if (xb) {
    v0 += xb[(size_t)r * D + t];
    v1 += xb[(size_t)r * D + t + 256];
  }
  v0 = tanhf(v0);
  v1 = tanhf(v1);
  __shared__ float s1[256], s2[256];
  s1[t] = v0 + v1;
  s2[t] = v0 * v0 + v1 * v1;
  __syncthreads();
  for (int off = 128; off > 0; off >>= 1) {
    if (t < off) { s1[t] += s1[t + off]; s2[t] += s2[t + off]; }
    __syncthreads();
  }
  const float mean = s1[0] * (1.f / (float)D);
  const float var = s2[0] * (1.f / (float)D) - mean * mean;
  const float rs = rsqrtf(var + 1e-5f);
  const float o0 = (v0 - mean) * rs * g[t] + beta[t];
  const float o1 = (v1 - mean) * rs * g[t + 256] + beta[t + 256];
  out32[(size_t)r * D + t] = o0;
  out32[(size_t)r * D + t + 256] = o1;
  if (out16) {
    out16[(size_t)r * D + t] = f2bf(o0);
    out16[(size_t)r * D + t + 256] = f2bf(o1);
  }
}

// ---------- final logits + sigmoid ----------
__global__ __launch_bounds__(256) void final_logit(
    const float* __restrict__ h, const float* __restrict__ Wc,
    const float* __restrict__ bc, float* __restrict__ out) {
  const int r = blockIdx.x;
  const int t = threadIdx.x;
  float p = h[(size_t)r * D + t] * Wc[t] + h[(size_t)r * D + t + 256] * Wc[t + 256];
  __shared__ float red[256];
  red[t] = p;
  __syncthreads();
  for (int off = 128; off > 0; off >>= 1) {
    if (t < off) red[t] += red[t + off];
    __syncthreads();
  }
  if (t == 0) out[r] = 1.f / (1.f + expf(-(red[0] + bc[0])));
}

extern "C" void kernel_launch(void* const* d_in, const int* in_sizes, int n_in,
                              void* d_out, int out_size, void* d_ws, size_t ws_size,
                              hipStream_t stream) {
  (void)n_in; (void)out_size; (void)ws_size;
  const float* node_feat = (const float*)d_in[0];
  const int* edge0 = (const int*)d_in[1];
  const int* edge1 = (const int*)d_in[2];
  const int* tidx = (const int*)d_in[3];
  const float* Wt = (const float*)d_in[4];
  const float* bt = (const float*)d_in[5];
  const float* Wf = (const float*)d_in[6];
  const float* bfp = (const float*)d_in[7];
  const float* w_att = (const float*)d_in[8];
  const float* b_att = (const float*)d_in[9];
  const float* gat_bias = (const float*)d_in[10];
  const float* Wp = (const float*)d_in[11];
  const float* bp = (const float*)d_in[12];
  const float* dnn_W = (const float*)d_in[13];
  const float* dnn_b = (const float*)d_in[14];
  const float* dnn_g = (const float*)d_in[15];
  const float* dnn_be = (const float*)d_in[16];
  const float* res_g = (const float*)d_in[17];
  const float* res_be = (const float*)d_in[18];
  const float* Wc = (const float*)d_in[19];
  const float* bc = (const float*)d_in[20];
  float* out = (float*)d_out;

  const int Nn = in_sizes[0] / D;   // 30000
  const int E = in_sizes[1] / 2;    // 300000
  const int B = in_sizes[3];        // 4096
  const int K_IN = in_sizes[4] / D; // 512
  const int Mp = (Nn + 127) / 128 * 128;  // padded node rows

  char* p = (char*)d_ws;
  auto alloc = [&](size_t bytes) -> char* {
    char* r = p;
    p += (bytes + 255) & ~(size_t)255;
    return r;
  };
  ushort_t* featb = (ushort_t*)alloc((size_t)Mp * D * 2);
  ushort_t* hb = (ushort_t*)alloc((size_t)Mp * D * 2);  // also nfb before hop GEMMs
  float* sd = (float*)alloc((size_t)Nn * 4);
  float* ss = (float*)alloc((size_t)Nn * 4);
  int* deg = (int*)alloc((size_t)Nn * 4);
  int* incl = (int*)alloc((size_t)Nn * 4);
  int* bsum = (int*)alloc(256 * 4);
  int* cursor = (int*)alloc((size_t)Nn * 4);
  int* row_start[2] = {(int*)alloc((size_t)(Nn + 1) * 4), (int*)alloc((size_t)(Nn + 1) * 4)};
  int* csr[2] = {(int*)alloc((size_t)E * 4), (int*)alloc((size_t)E * 4)};
  ushort_t* pWt = (ushort_t*)alloc((size_t)K_IN * D * 2);
  ushort_t* pWf = (ushort_t*)alloc((size_t)D * D * 2);
  ushort_t* pWp = (ushort_t*)alloc((size_t)D * D * 2);
  ushort_t* pDW[4];
  for (int i = 0; i < 4; ++i) pDW[i] = (ushort_t*)alloc((size_t)D * D * 2);
  ushort_t* g0b = (ushort_t*)alloc((size_t)B * D * 2);
  float* cur32 = (float*)alloc((size_t)B * D * 4);
  ushort_t* curb = (ushort_t*)alloc((size_t)B * D * 2);
  float* tmp32 = (float*)alloc((size_t)B * D * 4);
  float* ln32 = (float*)alloc((size_t)B * D * 4);
  ushort_t* lnb = (ushort_t*)alloc((size_t)B * D * 2);

  dim3 blk(256);
  const int nb = (Nn + 255) / 256;

  // ---- one-time packs / converts ----
  {
    const int wg = (D * D + 255) / 256;
    pack_weight<<<(K_IN * D + 255) / 256, blk, 0, stream>>>(Wt, pWt, K_IN, D);
    pack_weight<<<wg, blk, 0, stream>>>(Wf, pWf, D, D);
    pack_weight<<<wg, blk, 0, stream>>>(Wp, pWp, D, D);
    for (int i = 0; i < 4; ++i)
      pack_weight<<<wg, blk, 0, stream>>>(dnn_W + (size_t)i * D * D, pDW[i], D, D);
    conv_bf16_pad<<<((size_t)Mp * K_IN / 4 + 255) / 256, blk, 0, stream>>>(
        node_feat, hb /*nfb*/, Nn, Mp, K_IN);
  }

  // ---- CSR for both hops (feat-independent) ----
  const int* hops[2] = {edge1, edge0};  // processed hop1 then hop0
  for (int hp = 0; hp < 2; ++hp) {
    const int* di = hops[hp];
    const int* si = hops[hp] + E;
    hipMemsetAsync(deg, 0, (size_t)Nn * 4, stream);
    count_deg<<<(E + 255) / 256, blk, 0, stream>>>(di, deg, E);
    scan_block<<<nb, blk, 0, stream>>>(deg, incl, bsum, Nn);
    scan_sums<<<1, blk, 0, stream>>>(bsum, nb, &row_start[hp][Nn]);
    scan_finalize<<<nb, blk, 0, stream>>>(incl, deg, bsum, row_start[hp], cursor, Nn);
    fill_csr<<<(E + 255) / 256, blk, 0, stream>>>(di, si, cursor, csr[hp], E);
  }

  // ---- feat = node_feat @ Wt + bt (bf16 out) ----
  {
    dim3 grid(D / 128, Mp / 128);
    gemm_mfma<<<grid, blk, 0, stream>>>(hb /*nfb*/, pWt, bt, nullptr, featb, D, K_IN);
  }

  // ---- two GAT hops ----
  for (int hp = 0; hp < 2; ++hp) {
    dim3 grid(D / 128, Mp / 128);
    gemm_mfma<<<grid, blk, 0, stream>>>(featb, pWf, bfp, nullptr, hb, D, D);
    rowdot2<<<Nn, blk, 0, stream>>>(hb, w_att, sd, ss);
    gat_aggregate<<<Nn, blk, 0, stream>>>(featb, hb, sd, ss, b_att, gat_bias,
                                          row_start[hp], csr[hp]);
  }

  // ---- head ----
  gather_rows_b<<<B, blk, 0, stream>>>(featb, tidx, g0b);
  dim3 gridh(D / 128, B / 128);
  gemm_mfma<<<gridh, blk, 0, stream>>>(g0b, pWp, bp, cur32, curb, D, D);
  for (int r = 0; r < 2; ++r) {
    gemm_mfma<<<gridh, blk, 0, stream>>>(curb, pDW[r * 2], dnn_b + (size_t)(r * 2) * D,
                                         tmp32, nullptr, D, D);
    tanh_ln<<<B, blk, 0, stream>>>(tmp32, nullptr, dnn_g + (size_t)(r * 2) * D,
                                   dnn_be + (size_t)(r * 2) * D, ln32, lnb);
    gemm_mfma<<<gridh, blk, 0, stream>>>(lnb, pDW[r * 2 + 1], dnn_b + (size_t)(r * 2 + 1) * D,
                                         tmp32, nullptr, D, D);
    tanh_ln<<<B, blk, 0, stream>>>(tmp32, nullptr, dnn_g + (size_t)(r * 2 + 1) * D,
                                   dnn_be + (size_t)(r * 2 + 1) * D, ln32, lnb);
    // residual: new cur = LN(tanh(cur + ln32))
    tanh_ln<<<B, blk, 0, stream>>>(cur32, ln32, res_g + (size_t)r * D,
                                   res_be + (size_t)r * D, tmp32, curb);
    float* t = cur32; cur32 = tmp32; tmp32 = t;
  }
  final_logit<<<B, blk, 0, stream>>>(cur32, Wc, bc, out);
}

// Round 3
// 513.071 us; speedup vs baseline: 3.0932x; 1.3195x over previous
//
#include <hip/hip_runtime.h>

#define D 512
typedef unsigned short ushort_t;
typedef __attribute__((ext_vector_type(8))) short bf16x8;
typedef __attribute__((ext_vector_type(4))) float f32x4;

static __device__ __forceinline__ ushort_t f2bf(float f) {
  unsigned u = __float_as_uint(f);
  u += 0x7fffu + ((u >> 16) & 1u);  // RNE
  return (ushort_t)(u >> 16);
}
static __device__ __forceinline__ float bf2f(ushort_t h) {
  return __uint_as_float(((unsigned)h) << 16);
}

static __device__ __forceinline__ void gld_lds16(const void* g, void* lds) {
  __builtin_amdgcn_global_load_lds(
      (const __attribute__((address_space(1))) unsigned int*)g,
      (__attribute__((address_space(3))) unsigned int*)lds, 16, 0, 0);
}

// ---------- weight pack: W[K][N] fp32 -> fragment-ready bf16 ----------
__global__ __launch_bounds__(256) void pack_weight(
    const float* __restrict__ W, ushort_t* __restrict__ out, int K, int N) {
  int i = blockIdx.x * 256 + threadIdx.x;
  if (i >= K * N) return;
  const int k = i / N, n = i - k * N;
  const int nt = n >> 4, col = n & 15, kt = k >> 5, kg = (k >> 3) & 3, j = k & 7;
  out[(((size_t)nt * (K >> 5) + kt) << 9) + ((kg << 4) + col) * 8 + j] = f2bf(W[i]);
}

// ---------- fp32 -> bf16 row-major with row padding ----------
__global__ __launch_bounds__(256) void conv_bf16_pad(
    const float* __restrict__ in, ushort_t* __restrict__ out, int M, int Mp, int K) {
  const size_t i4 = ((size_t)blockIdx.x * 256 + threadIdx.x) * 4;
  if (i4 >= (size_t)Mp * K) return;
  const int row = (int)(i4 / K);
  ushort4 o;
  if (row < M) {
    const float4 v = *reinterpret_cast<const float4*>(&in[i4]);
    o.x = f2bf(v.x); o.y = f2bf(v.y); o.z = f2bf(v.z); o.w = f2bf(v.w);
  } else {
    o.x = o.y = o.z = o.w = 0;
  }
  *reinterpret_cast<ushort4*>(&out[i4]) = o;
}

// ---------- MFMA GEMM: C[Mp,N] = A[Mp,K](bf16) @ Wpack + bias ----------
__global__ __launch_bounds__(256) void gemm_mfma(
    const ushort_t* __restrict__ A, const ushort_t* __restrict__ Bp,
    const float* __restrict__ bias, float* __restrict__ C32,
    ushort_t* __restrict__ C16, int N, int K) {
  __shared__ __align__(16) ushort_t As[8 * 512];
  __shared__ __align__(16) ushort_t Bs[8 * 512];
  const int tid = threadIdx.x;
  const int lane = tid & 63;
  const int wid = tid >> 6;
  const int m0 = blockIdx.y * 128;
  const int n0 = blockIdx.x * 128;
  const int wm = wid >> 1, wn = wid & 1;
  const int arow = lane & 15;
  const int akoff = (lane >> 4) * 8;
  const int kt32 = K >> 5;
  f32x4 acc[4][4] = {};
  ushort_t* as0 = &As[(wid * 2 + 0) * 512];
  ushort_t* as1 = &As[(wid * 2 + 1) * 512];
  ushort_t* bs0 = &Bs[(wid * 2 + 0) * 512];
  ushort_t* bs1 = &Bs[(wid * 2 + 1) * 512];
  for (int k0 = 0; k0 < K; k0 += 32) {
    const ushort_t* ga0 = &A[(size_t)(m0 + (wid * 2 + 0) * 16 + arow) * K + k0 + akoff];
    const ushort_t* ga1 = &A[(size_t)(m0 + (wid * 2 + 1) * 16 + arow) * K + k0 + akoff];
    gld_lds16(ga0, as0);
    gld_lds16(ga1, as1);
    const ushort_t* gb0 = &Bp[(((size_t)(n0 / 16 + wid * 2 + 0) * kt32 + (k0 >> 5)) << 9) + lane * 8];
    const ushort_t* gb1 = &Bp[(((size_t)(n0 / 16 + wid * 2 + 1) * kt32 + (k0 >> 5)) << 9) + lane * 8];
    gld_lds16(gb0, bs0);
    gld_lds16(gb1, bs1);
    __syncthreads();
    bf16x8 af[4], bf[4];
#pragma unroll
    for (int mi = 0; mi < 4; ++mi)
      af[mi] = *reinterpret_cast<const bf16x8*>(&As[(wm * 4 + mi) * 512 + lane * 8]);
#pragma unroll
    for (int ni = 0; ni < 4; ++ni)
      bf[ni] = *reinterpret_cast<const bf16x8*>(&Bs[(wn * 4 + ni) * 512 + lane * 8]);
#pragma unroll
    for (int mi = 0; mi < 4; ++mi)
#pragma unroll
      for (int ni = 0; ni < 4; ++ni)
        acc[mi][ni] = __builtin_amdgcn_mfma_f32_16x16x32_bf16(af[mi], bf[ni], acc[mi][ni], 0, 0, 0);
    __syncthreads();
  }
#pragma unroll
  for (int mi = 0; mi < 4; ++mi) {
    const int row = m0 + wm * 64 + mi * 16 + ((lane >> 4) << 2);
#pragma unroll
    for (int ni = 0; ni < 4; ++ni) {
      const int col = n0 + wn * 64 + ni * 16 + (lane & 15);
      const float bv = bias[col];
#pragma unroll
      for (int r = 0; r < 4; ++r) {
        const float v = acc[mi][ni][r] + bv;
        const size_t o = (size_t)(row + r) * N + col;
        if (C32) C32[o] = v;
        if (C16) C16[o] = f2bf(v);
      }
    }
  }
}

// ---------- per-row double dot, one wave per row ----------
__global__ __launch_bounds__(256) void rowdot2_w(
    const ushort_t* __restrict__ hb, const float* __restrict__ w_att,
    float* __restrict__ sd, float* __restrict__ ss, int Nn) {
  const int r = blockIdx.x * 4 + (threadIdx.x >> 6);
  const int lane = threadIdx.x & 63;
  if (r >= Nn) return;
  const bf16x8 hv = *reinterpret_cast<const bf16x8*>(&hb[(size_t)r * D + lane * 8]);
  float d0 = 0.f, d1 = 0.f;
#pragma unroll
  for (int q = 0; q < 8; ++q) {
    const float v = bf2f((ushort_t)hv[q]);
    d0 += v * w_att[lane * 8 + q];
    d1 += v * w_att[D + lane * 8 + q];
  }
#pragma unroll
  for (int off = 32; off > 0; off >>= 1) {
    d0 += __shfl_xor(d0, off);
    d1 += __shfl_xor(d1, off);
  }
  if (lane == 0) { sd[r] = d0; ss[r] = d1; }
}

// ---------- CSR build ----------
__global__ void count_deg(const int* __restrict__ di, int* __restrict__ deg, int E) {
  const int e = blockIdx.x * blockDim.x + threadIdx.x;
  if (e < E) atomicAdd(&deg[di[e]], 1);
}

__global__ __launch_bounds__(256) void scan_block(
    const int* __restrict__ deg, int* __restrict__ incl, int* __restrict__ bsum, int n) {
  __shared__ int buf[256];
  const int t = threadIdx.x;
  const int i = blockIdx.x * 256 + t;
  const int v = (i < n) ? deg[i] : 0;
  buf[t] = v;
  __syncthreads();
  for (int off = 1; off < 256; off <<= 1) {
    const int y = (t >= off) ? buf[t - off] : 0;
    __syncthreads();
    buf[t] += y;
    __syncthreads();
  }
  if (i < n) incl[i] = buf[t];
  if (t == 255) bsum[blockIdx.x] = buf[255];
}

__global__ __launch_bounds__(256) void scan_sums(
    int* __restrict__ bsum, int nb, int* __restrict__ row_total) {
  __shared__ int buf[256];
  const int t = threadIdx.x;
  const int v = (t < nb) ? bsum[t] : 0;
  buf[t] = v;
  __syncthreads();
  for (int off = 1; off < 256; off <<= 1) {
    const int y = (t >= off) ? buf[t - off] : 0;
    __syncthreads();
    buf[t] += y;
    __syncthreads();
  }
  if (t < nb) bsum[t] = buf[t] - v;  // exclusive
  if (t == 0) *row_total = buf[255];
}

__global__ __launch_bounds__(256) void scan_finalize(
    const int* __restrict__ incl, const int* __restrict__ deg,
    const int* __restrict__ bsum, int* __restrict__ row_start,
    int* __restrict__ cursor, int n) {
  const int i = blockIdx.x * 256 + threadIdx.x;
  if (i >= n) return;
  const int v = incl[i] - deg[i] + bsum[i >> 8];
  row_start[i] = v;
  cursor[i] = v;
}

__global__ void fill_csr(const int* __restrict__ di, const int* __restrict__ si,
                         int* __restrict__ cursor, int* __restrict__ csr_src,
                         int* __restrict__ csr_dst, int E) {
  const int e = blockIdx.x * blockDim.x + threadIdx.x;
  if (e < E) {
    const int d = di[e];
    const int p = atomicAdd(&cursor[d], 1);
    csr_src[p] = si[e];
    csr_dst[p] = d;
  }
}

// ---------- per-edge logits: e = tanh(sd[dst] + ss[src] + b) ----------
__global__ __launch_bounds__(256) void edge_logits(
    const int* __restrict__ csr_src, const int* __restrict__ csr_dst,
    const float* __restrict__ sd, const float* __restrict__ ss,
    const float* __restrict__ b_att_p, float* __restrict__ edge_e, int E) {
  const int j = blockIdx.x * 256 + threadIdx.x;
  if (j < E) edge_e[j] = tanhf(sd[csr_dst[j]] + ss[csr_src[j]] + b_att_p[0]);
}

// ---------- GAT softmax + aggregate, one wave per dst ----------
__global__ __launch_bounds__(256) void gat_aggregate_w(
    ushort_t* __restrict__ featb, const ushort_t* __restrict__ hb,
    const float* __restrict__ edge_e, const float* __restrict__ gat_bias,
    const int* __restrict__ row_start, const int* __restrict__ csr_src, int Nn) {
  const int dst = blockIdx.x * 4 + (threadIdx.x >> 6);
  const int lane = threadIdx.x & 63;
  if (dst >= Nn) return;
  const int beg = row_start[dst];
  const int end = row_start[dst + 1];
  // wave softmax over segment
  float m = -1e30f;
  for (int j = beg + lane; j < end; j += 64) m = fmaxf(m, edge_e[j]);
#pragma unroll
  for (int off = 32; off > 0; off >>= 1) m = fmaxf(m, __shfl_xor(m, off));
  float s = 0.f;
  for (int j = beg + lane; j < end; j += 64) s += expf(edge_e[j] - m);
#pragma unroll
  for (int off = 32; off > 0; off >>= 1) s += __shfl_xor(s, off);
  const float inv = (s > 0.f) ? 1.f / s : 0.f;
  // aggregation: lane covers 8 contiguous columns
  float acc[8] = {};
  for (int j = beg; j < end; ++j) {
    const int sidx = csr_src[j];
    const float w = expf(edge_e[j] - m) * inv;
    const bf16x8 hv = *reinterpret_cast<const bf16x8*>(&hb[(size_t)sidx * D + lane * 8]);
#pragma unroll
    for (int q = 0; q < 8; ++q) acc[q] += w * bf2f((ushort_t)hv[q]);
  }
  const size_t o = (size_t)dst * D + lane * 8;
  bf16x8 fv = *reinterpret_cast<const bf16x8*>(&featb[o]);
#pragma unroll
  for (int q = 0; q < 8; ++q) {
    const float f = (bf2f((ushort_t)fv[q]) + acc[q] + gat_bias[lane * 8 + q]) * 0.5f;
    fv[q] = (short)f2bf(f);
  }
  *reinterpret_cast<bf16x8*>(&featb[o]) = fv;
}

// ---------- gather bf16 rows ----------
__global__ __launch_bounds__(256) void gather_rows_b(
    const ushort_t* __restrict__ featb, const int* __restrict__ idx,
    ushort_t* __restrict__ out) {
  const int b = blockIdx.x;
  const int t = threadIdx.x;
  const int r = idx[b];
  *reinterpret_cast<ushort2*>(&out[(size_t)b * D + t * 2]) =
      *reinterpret_cast<const ushort2*>(&featb[(size_t)r * D + t * 2]);
}

// ---------- fused tanh + LayerNorm, fp32 + bf16 outputs ----------
__global__ __launch_bounds__(256) void tanh_ln(
    const float* __restrict__ xa, const float* __restrict__ xb,
    const float* __restrict__ g, const float* __restrict__ beta,
    float* __restrict__ out32, ushort_t* __restrict__ out16) {
  const int r = blockIdx.x;
  const int t = threadIdx.x;
  float v0 = xa[(size_t)r * D + t];
  float v1 = xa[(size_t)r * D + t + 256];
  if (xb) {
    v0 += xb[(size_t)r * D + t];
    v1 += xb[(size_t)r * D + t + 256];
  }
  v0 = tanhf(v0);
  v1 = tanhf(v1);
  __shared__ float s1[256], s2[256];
  s1[t] = v0 + v1;
  s2[t] = v0 * v0 + v1 * v1;
  __syncthreads();
  for (int off = 128; off > 0; off >>= 1) {
    if (t < off) { s1[t] += s1[t + off]; s2[t] += s2[t + off]; }
    __syncthreads();
  }
  const float mean = s1[0] * (1.f / (float)D);
  const float var = s2[0] * (1.f / (float)D) - mean * mean;
  const float rs = rsqrtf(var + 1e-5f);
  const float o0 = (v0 - mean) * rs * g[t] + beta[t];
  const float o1 = (v1 - mean) * rs * g[t + 256] + beta[t + 256];
  out32[(size_t)r * D + t] = o0;
  out32[(size_t)r * D + t + 256] = o1;
  if (out16) {
    out16[(size_t)r * D + t] = f2bf(o0);
    out16[(size_t)r * D + t + 256] = f2bf(o1);
  }
}

// ---------- final logits + sigmoid ----------
__global__ __launch_bounds__(256) void final_logit(
    const float* __restrict__ h, const float* __restrict__ Wc,
    const float* __restrict__ bc, float* __restrict__ out) {
  const int r = blockIdx.x;
  const int t = threadIdx.x;
  float p = h[(size_t)r * D + t] * Wc[t] + h[(size_t)r * D + t + 256] * Wc[t + 256];
  __shared__ float red[256];
  red[t] = p;
  __syncthreads();
  for (int off = 128; off > 0; off >>= 1) {
    if (t < off) red[t] += red[t + off];
    __syncthreads();
  }
  if (t == 0) out[r] = 1.f / (1.f + expf(-(red[0] + bc[0])));
}

extern "C" void kernel_launch(void* const* d_in, const int* in_sizes, int n_in,
                              void* d_out, int out_size, void* d_ws, size_t ws_size,
                              hipStream_t stream) {
  (void)n_in; (void)out_size; (void)ws_size;
  const float* node_feat = (const float*)d_in[0];
  const int* edge0 = (const int*)d_in[1];
  const int* edge1 = (const int*)d_in[2];
  const int* tidx = (const int*)d_in[3];
  const float* Wt = (const float*)d_in[4];
  const float* bt = (const float*)d_in[5];
  const float* Wf = (const float*)d_in[6];
  const float* bfp = (const float*)d_in[7];
  const float* w_att = (const float*)d_in[8];
  const float* b_att = (const float*)d_in[9];
  const float* gat_bias = (const float*)d_in[10];
  const float* Wp = (const float*)d_in[11];
  const float* bp = (const float*)d_in[12];
  const float* dnn_W = (const float*)d_in[13];
  const float* dnn_b = (const float*)d_in[14];
  const float* dnn_g = (const float*)d_in[15];
  const float* dnn_be = (const float*)d_in[16];
  const float* res_g = (const float*)d_in[17];
  const float* res_be = (const float*)d_in[18];
  const float* Wc = (const float*)d_in[19];
  const float* bc = (const float*)d_in[20];
  float* out = (float*)d_out;

  const int Nn = in_sizes[0] / D;   // 30000
  const int E = in_sizes[1] / 2;    // 300000
  const int B = in_sizes[3];        // 4096
  const int K_IN = in_sizes[4] / D; // 512
  const int Mp = (Nn + 127) / 128 * 128;

  char* p = (char*)d_ws;
  auto alloc = [&](size_t bytes) -> char* {
    char* r = p;
    p += (bytes + 255) & ~(size_t)255;
    return r;
  };
  ushort_t* featb = (ushort_t*)alloc((size_t)Mp * D * 2);
  ushort_t* hb = (ushort_t*)alloc((size_t)Mp * D * 2);  // also nfb before hop GEMMs
  float* sd = (float*)alloc((size_t)Nn * 4);
  float* ss = (float*)alloc((size_t)Nn * 4);
  int* deg = (int*)alloc((size_t)Nn * 4);
  int* incl = (int*)alloc((size_t)Nn * 4);
  int* bsum = (int*)alloc(256 * 4);
  int* cursor = (int*)alloc((size_t)Nn * 4);
  int* row_start[2] = {(int*)alloc((size_t)(Nn + 1) * 4), (int*)alloc((size_t)(Nn + 1) * 4)};
  int* csr_s[2] = {(int*)alloc((size_t)E * 4), (int*)alloc((size_t)E * 4)};
  int* csr_d[2] = {(int*)alloc((size_t)E * 4), (int*)alloc((size_t)E * 4)};
  float* edge_e = (float*)alloc((size_t)E * 4);
  ushort_t* pWt = (ushort_t*)alloc((size_t)K_IN * D * 2);
  ushort_t* pWf = (ushort_t*)alloc((size_t)D * D * 2);
  ushort_t* pWp = (ushort_t*)alloc((size_t)D * D * 2);
  ushort_t* pDW[4];
  for (int i = 0; i < 4; ++i) pDW[i] = (ushort_t*)alloc((size_t)D * D * 2);
  ushort_t* g0b = (ushort_t*)alloc((size_t)B * D * 2);
  float* cur32 = (float*)alloc((size_t)B * D * 4);
  ushort_t* curb = (ushort_t*)alloc((size_t)B * D * 2);
  float* tmp32 = (float*)alloc((size_t)B * D * 4);
  float* ln32 = (float*)alloc((size_t)B * D * 4);
  ushort_t* lnb = (ushort_t*)alloc((size_t)B * D * 2);

  dim3 blk(256);
  const int nb = (Nn + 255) / 256;
  const int nw4 = (Nn + 3) / 4;

  // ---- one-time packs / converts ----
  {
    const int wg = (D * D + 255) / 256;
    pack_weight<<<(K_IN * D + 255) / 256, blk, 0, stream>>>(Wt, pWt, K_IN, D);
    pack_weight<<<wg, blk, 0, stream>>>(Wf, pWf, D, D);
    pack_weight<<<wg, blk, 0, stream>>>(Wp, pWp, D, D);
    for (int i = 0; i < 4; ++i)
      pack_weight<<<wg, blk, 0, stream>>>(dnn_W + (size_t)i * D * D, pDW[i], D, D);
    conv_bf16_pad<<<((size_t)Mp * K_IN / 4 + 255) / 256, blk, 0, stream>>>(
        node_feat, hb /*nfb*/, Nn, Mp, K_IN);
  }

  // ---- CSR for both hops (feat-independent) ----
  const int* hops[2] = {edge1, edge0};  // processed hop1 then hop0
  for (int hp = 0; hp < 2; ++hp) {
    const int* di = hops[hp];
    const int* si = hops[hp] + E;
    hipMemsetAsync(deg, 0, (size_t)Nn * 4, stream);
    count_deg<<<(E + 255) / 256, blk, 0, stream>>>(di, deg, E);
    scan_block<<<nb, blk, 0, stream>>>(deg, incl, bsum, Nn);
    scan_sums<<<1, blk, 0, stream>>>(bsum, nb, &row_start[hp][Nn]);
    scan_finalize<<<nb, blk, 0, stream>>>(incl, deg, bsum, row_start[hp], cursor, Nn);
    fill_csr<<<(E + 255) / 256, blk, 0, stream>>>(di, si, cursor, csr_s[hp], csr_d[hp], E);
  }

  // ---- feat = node_feat @ Wt + bt (bf16 out) ----
  {
    dim3 grid(D / 128, Mp / 128);
    gemm_mfma<<<grid, blk, 0, stream>>>(hb /*nfb*/, pWt, bt, nullptr, featb, D, K_IN);
  }

  // ---- two GAT hops ----
  for (int hp = 0; hp < 2; ++hp) {
    dim3 grid(D / 128, Mp / 128);
    gemm_mfma<<<grid, blk, 0, stream>>>(featb, pWf, bfp, nullptr, hb, D, D);
    rowdot2_w<<<nw4, blk, 0, stream>>>(hb, w_att, sd, ss, Nn);
    edge_logits<<<(E + 255) / 256, blk, 0, stream>>>(csr_s[hp], csr_d[hp], sd, ss,
                                                     b_att, edge_e, E);
    gat_aggregate_w<<<nw4, blk, 0, stream>>>(featb, hb, edge_e, gat_bias,
                                             row_start[hp], csr_s[hp], Nn);
  }

  // ---- head ----
  gather_rows_b<<<B, blk, 0, stream>>>(featb, tidx, g0b);
  dim3 gridh(D / 128, B / 128);
  gemm_mfma<<<gridh, blk, 0, stream>>>(g0b, pWp, bp, cur32, curb, D, D);
  for (int r = 0; r < 2; ++r) {
    gemm_mfma<<<gridh, blk, 0, stream>>>(curb, pDW[r * 2], dnn_b + (size_t)(r * 2) * D,
                                         tmp32, nullptr, D, D);
    tanh_ln<<<B, blk, 0, stream>>>(tmp32, nullptr, dnn_g + (size_t)(r * 2) * D,
                                   dnn_be + (size_t)(r * 2) * D, ln32, lnb);
    gemm_mfma<<<gridh, blk, 0, stream>>>(lnb, pDW[r * 2 + 1], dnn_b + (size_t)(r * 2 + 1) * D,
                                         tmp32, nullptr, D, D);
    tanh_ln<<<B, blk, 0, stream>>>(tmp32, nullptr, dnn_g + (size_t)(r * 2 + 1) * D,
                                   dnn_be + (size_t)(r * 2 + 1) * D, ln32, lnb);
    tanh_ln<<<B, blk, 0, stream>>>(cur32, ln32, res_g + (size_t)r * D,
                                   res_be + (size_t)r * D, tmp32, curb);
    float* t = cur32; cur32 = tmp32; tmp32 = t;
  }
  final_logit<<<B, blk, 0, stream>>>(cur32, Wc, bc, out);
}